// Round 9
// baseline (229.701 us; speedup 1.0000x reference)
//
#include <hip/hip_runtime.h>

#define N_NODES 50000
#define N_EDGES 800000
#define NFEAT   256
#define NHID    128
#define NCLASS  47
#define H2P     48    // padded h2 row (bf16)
#define CSR_MAX (N_EDGES + 7 * N_NODES)   // every segment padded to multiple of 8
#define NSUB    8     // sub-bucketed degree counters (contention / NSUB)
#define AG1_NPW 8     // nodes per wave in agg1

typedef __attribute__((ext_vector_type(8))) short short8v;
typedef __attribute__((ext_vector_type(4))) float f32x4;

__device__ __forceinline__ ushort f2bf(float f) {
    unsigned u = __float_as_uint(f);
    unsigned r = (u + 0x7FFF + ((u >> 16) & 1)) >> 16;   // round-to-nearest-even
    return (ushort)r;
}
__device__ __forceinline__ float bf2f(ushort b) {
    return __uint_as_float(((unsigned)b) << 16);
}
__device__ __forceinline__ float blo(unsigned u) { return __uint_as_float(u << 16); }
__device__ __forceinline__ float bhi(unsigned u) { return __uint_as_float(u & 0xFFFF0000u); }

// ---------------- weight prep: transpose+convert W1, W2 to bf16 once ----------------

__global__ void wprep_kernel(const float* __restrict__ W1, const float* __restrict__ W2,
                             ushort* __restrict__ w1t, ushort* __restrict__ w2t) {
    int t = blockIdx.x * blockDim.x + threadIdx.x;
    if (t < NFEAT * NHID) {              // read coalesced over c-fast
        int k = t >> 7, c = t & 127;
        w1t[c * NFEAT + k] = f2bf(W1[(size_t)k * NHID + c]);
    }
    if (t < NHID * H2P) {
        int k = t / H2P, c = t % H2P;
        w2t[c * NHID + k] = (c < NCLASS) ? f2bf(W2[(size_t)k * NCLASS + c]) : 0;
    }
}

// ---------------- CSR build ----------------

__global__ void zero_init_kernel(unsigned long long* __restrict__ packed8,
                                 int2* __restrict__ csr, int* __restrict__ total) {
    int i = blockIdx.x * blockDim.x + threadIdx.x;
    if (i < CSR_MAX) csr[i] = make_int2(0, 0);   // src=0, w=+0.0f (pad entries)
    if (i < N_NODES * NSUB) packed8[i] = 0ull;
    if (i == 0) *total = 0;
}

__global__ void degcnt_kernel(const int* __restrict__ dst, const float* __restrict__ w,
                              unsigned long long* __restrict__ packed8,
                              int* __restrict__ pos, int E) {
    int e = blockIdx.x * blockDim.x + threadIdx.x;
    if (e >= E) return;
    int d = dst[e];
    int b = e & (NSUB - 1);
    unsigned fx = __float2uint_rn(w[e] * 1048576.0f);
    unsigned long long old = atomicAdd(&packed8[(size_t)d * NSUB + b],
                                       (1ull << 40) | (unsigned long long)fx);
    pos[e] = (int)(old >> 40);
}

__global__ __launch_bounds__(256) void segalloc_kernel(const unsigned long long* __restrict__ packed8,
                                                       int* __restrict__ counts,
                                                       float* __restrict__ dinv,
                                                       int* __restrict__ row_start,
                                                       int* __restrict__ sub_base,
                                                       int* __restrict__ total, int n) {
    __shared__ int s[256];
    __shared__ int base_s;
    int t = threadIdx.x;
    int i = blockIdx.x * 256 + t;
    int v = 0;
    if (i < n) {
        int cnt = 0;
        unsigned long long ws = 0;
        int sb[NSUB];
        #pragma unroll
        for (int b = 0; b < NSUB; ++b) {
            unsigned long long pk = packed8[(size_t)i * NSUB + b];
            sb[b] = cnt;
            cnt += (int)(pk >> 40);
            ws += (pk & 0xFFFFFFFFFFull);
        }
        counts[i] = cnt;
        float deg = 1.0f + (float)ws * (1.0f / 1048576.0f);
        dinv[i] = rsqrtf(deg);
        #pragma unroll
        for (int b = 0; b < NSUB; b += 4)
            *(int4*)&sub_base[(size_t)i * NSUB + b] = make_int4(sb[b], sb[b+1], sb[b+2], sb[b+3]);
        v = (cnt + 7) & ~7;
    }
    s[t] = v;
    __syncthreads();
    #pragma unroll
    for (int off = 1; off < 256; off <<= 1) {
        int x = s[t];
        if (t >= off) x += s[t - off];
        __syncthreads();
        s[t] = x;
        __syncthreads();
    }
    if (t == 255) base_s = atomicAdd(total, s[255]);
    __syncthreads();
    if (i < n) row_start[i] = base_s + s[t] - v;
}

__global__ void scatter_kernel(const int* __restrict__ src, const int* __restrict__ dst,
                               const float* __restrict__ w, const int* __restrict__ pos,
                               const float* __restrict__ dinv,
                               const int* __restrict__ row_start,
                               const int* __restrict__ sub_base,
                               int2* __restrict__ csr, int E) {
    int e = blockIdx.x * blockDim.x + threadIdx.x;
    if (e >= E) return;
    int d = dst[e], s = src[e];
    int b = e & (NSUB - 1);
    int p = row_start[d] + sub_base[(size_t)d * NSUB + b] + pos[e];
    int2 pr;
    pr.x = s;
    pr.y = __float_as_int(dinv[s] * w[e] * dinv[d]);
    csr[p] = pr;
}

// ---------------- Layer 1 GEMM (MFMA bf16): h1b = bf16(x @ W1) ----------------

__global__ __launch_bounds__(256) void gemm1_kernel(const float* __restrict__ x,
                                                    const ushort* __restrict__ w1t,
                                                    ushort* __restrict__ h1b) {
    __shared__ __align__(16) ushort xs[64][72];
    __shared__ __align__(16) ushort ws[128][72];
    int tid = threadIdx.x;
    int node0 = blockIdx.x * 64;
    int wave = tid >> 6, l = tid & 63;
    int fr = l & 15, fq = l >> 4;
    int r0 = (wave >> 1) * 32;
    int c0 = (wave & 1) * 64;

    f32x4 acc[2][4] = {};

    for (int kk0 = 0; kk0 < NFEAT; kk0 += 64) {
        {
            int row = tid >> 2, q = tid & 3;
            int srow = node0 + row; if (srow >= N_NODES) srow = N_NODES - 1;
            const float4* src = (const float4*)(x + (size_t)srow * NFEAT + kk0 + q * 16);
            ushort tmp[16];
            #pragma unroll
            for (int i = 0; i < 4; ++i) {
                float4 v = src[i];
                tmp[i * 4 + 0] = f2bf(v.x); tmp[i * 4 + 1] = f2bf(v.y);
                tmp[i * 4 + 2] = f2bf(v.z); tmp[i * 4 + 3] = f2bf(v.w);
            }
            #pragma unroll
            for (int i = 0; i < 2; ++i)
                *(short8v*)&xs[row][q * 16 + i * 8] = *(short8v*)&tmp[i * 8];
        }
        {
            int rr = tid >> 3;
            int cq = tid & 7;
            #pragma unroll
            for (int i = 0; i < 4; ++i) {
                int row = rr + i * 32;
                *(short8v*)&ws[row][cq * 8] =
                    *(const short8v*)&w1t[(size_t)row * NFEAT + kk0 + cq * 8];
            }
        }
        __syncthreads();
        short8v a[2][2], b[4][2];
        #pragma unroll
        for (int m = 0; m < 2; ++m)
            #pragma unroll
            for (int kf = 0; kf < 2; ++kf)
                a[m][kf] = *(const short8v*)&xs[r0 + m * 16 + fr][kf * 32 + fq * 8];
        #pragma unroll
        for (int n = 0; n < 4; ++n)
            #pragma unroll
            for (int kf = 0; kf < 2; ++kf)
                b[n][kf] = *(const short8v*)&ws[c0 + n * 16 + fr][kf * 32 + fq * 8];
        #pragma unroll
        for (int m = 0; m < 2; ++m)
            #pragma unroll
            for (int n = 0; n < 4; ++n)
                #pragma unroll
                for (int kf = 0; kf < 2; ++kf)
                    acc[m][n] = __builtin_amdgcn_mfma_f32_16x16x32_bf16(
                        a[m][kf], b[n][kf], acc[m][n], 0, 0, 0);
        __syncthreads();
    }
    #pragma unroll
    for (int m = 0; m < 2; ++m) {
        #pragma unroll
        for (int n = 0; n < 4; ++n) {
            #pragma unroll
            for (int j = 0; j < 4; ++j) {
                int gr = node0 + r0 + m * 16 + fq * 4 + j;
                if (gr < N_NODES)
                    h1b[(size_t)gr * NHID + c0 + n * 16 + fr] = f2bf(acc[m][n][j]);
            }
        }
    }
}

// ---------------- Aggregation 1 (feature-sliced, XCD-resident) ----------------
// slice = blockIdx & 7 -> one of 8 XCDs (round-robin dispatch); each XCD gathers
// only a 50000 x 16-feat slice (1.6 MB, L2-resident). Lane: el=lane>>3 (8 edges
// per instruction), fp=lane&7 (2 feats, 4B). Edge loop 2x unrolled (16 in flight).

__global__ __launch_bounds__(256) void agg1_kernel(const ushort* __restrict__ h1b,
                                                   const int* __restrict__ row_start,
                                                   const int* __restrict__ counts,
                                                   const int2* __restrict__ csr,
                                                   const float* __restrict__ dinv,
                                                   const float* __restrict__ b1,
                                                   ushort* __restrict__ haggb) {
    int slice = blockIdx.x & 7;
    int chunk = blockIdx.x >> 3;
    int wv = threadIdx.x >> 6;
    int l = threadIdx.x & 63;
    int el = l >> 3, fp = l & 7;
    int f0 = slice * 16 + fp * 2;
    const ushort* rowp = h1b + f0;
    float2 bb = *(const float2*)(b1 + f0);
    int ibase = (chunk * 4 + wv) * AG1_NPW;

    for (int ni = 0; ni < AG1_NPW; ++ni) {
        int i = ibase + ni;
        if (i >= N_NODES) return;
        float di = dinv[i];
        float sc = (el == 0) ? di * di : 0.f;
        unsigned sv = *(const unsigned*)(rowp + (size_t)i * NHID);
        float ax = sc * blo(sv), ay = sc * bhi(sv);

        int lo = row_start[i], hi = lo + ((counts[i] + 7) & ~7);
        int e = lo;
        for (; e + 16 <= hi; e += 16) {
            int2 p1 = csr[e + el];
            int2 p2 = csr[e + 8 + el];
            unsigned v1 = *(const unsigned*)(rowp + (size_t)p1.x * NHID);
            unsigned v2 = *(const unsigned*)(rowp + (size_t)p2.x * NHID);
            float w1 = __int_as_float(p1.y), w2 = __int_as_float(p2.y);
            ax = fmaf(w1, blo(v1), ax); ay = fmaf(w1, bhi(v1), ay);
            ax = fmaf(w2, blo(v2), ax); ay = fmaf(w2, bhi(v2), ay);
        }
        if (e < hi) {
            int2 p1 = csr[e + el];
            unsigned v1 = *(const unsigned*)(rowp + (size_t)p1.x * NHID);
            float w1 = __int_as_float(p1.y);
            ax = fmaf(w1, blo(v1), ax); ay = fmaf(w1, bhi(v1), ay);
        }
        // reduce across the 8 edge-groups (lane bits 3,4,5)
        ax += __shfl_xor(ax, 8);  ay += __shfl_xor(ay, 8);
        ax += __shfl_xor(ax, 16); ay += __shfl_xor(ay, 16);
        ax += __shfl_xor(ax, 32); ay += __shfl_xor(ay, 32);
        if (el == 0) {
            ax = fmaxf(ax + bb.x, 0.f);
            ay = fmaxf(ay + bb.y, 0.f);
            *(unsigned*)(haggb + (size_t)i * NHID + f0) =
                (unsigned)f2bf(ax) | ((unsigned)f2bf(ay) << 16);
        }
    }
}

// ---------------- Layer 2 GEMM (MFMA bf16): h2b = bf16(hagg @ W2), rows padded to 48 ----------------

__global__ __launch_bounds__(256) void gemm2_kernel(const ushort* __restrict__ haggb,
                                                    const ushort* __restrict__ w2t,
                                                    ushort* __restrict__ h2b) {
    __shared__ __align__(16) ushort ha[64][136];
    __shared__ __align__(16) ushort wt[48][136];
    int tid = threadIdx.x;
    int node0 = blockIdx.x * 64;
    {
        int row = tid >> 2, q = tid & 3;
        int srow = node0 + row; if (srow >= N_NODES) srow = N_NODES - 1;
        const short8v* src = (const short8v*)(haggb + (size_t)srow * NHID + q * 32);
        #pragma unroll
        for (int i = 0; i < 4; ++i)
            *(short8v*)&ha[row][q * 32 + i * 8] = src[i];
    }
    {
        #pragma unroll
        for (int i = 0; i < 3; ++i) {
            int id = tid + i * 256;
            int row = id >> 4, cq = id & 15;
            *(short8v*)&wt[row][cq * 8] =
                *(const short8v*)&w2t[(size_t)row * NHID + cq * 8];
        }
    }
    __syncthreads();
    int wave = tid >> 6, l = tid & 63;
    int fr = l & 15, fq = l >> 4;
    int r0 = wave * 16;
    short8v a[4], b[3][4];
    #pragma unroll
    for (int kf = 0; kf < 4; ++kf)
        a[kf] = *(const short8v*)&ha[r0 + fr][kf * 32 + fq * 8];
    #pragma unroll
    for (int n = 0; n < 3; ++n)
        #pragma unroll
        for (int kf = 0; kf < 4; ++kf)
            b[n][kf] = *(const short8v*)&wt[n * 16 + fr][kf * 32 + fq * 8];
    f32x4 acc[3] = {};
    #pragma unroll
    for (int n = 0; n < 3; ++n)
        #pragma unroll
        for (int kf = 0; kf < 4; ++kf)
            acc[n] = __builtin_amdgcn_mfma_f32_16x16x32_bf16(a[kf], b[n][kf], acc[n], 0, 0, 0);
    #pragma unroll
    for (int n = 0; n < 3; ++n) {
        #pragma unroll
        for (int j = 0; j < 4; ++j) {
            int gr = node0 + r0 + fq * 4 + j;
            int col = n * 16 + fr;
            if (gr < N_NODES && col < H2P)
                h2b[(size_t)gr * H2P + col] = (col < NCLASS) ? f2bf(acc[n][j]) : 0;
        }
    }
}

// ---------------- Aggregation 2 + bias + log_softmax -> out ----------------

__global__ __launch_bounds__(256) void agg2_kernel(const ushort* __restrict__ h2b,
                                                   const int* __restrict__ row_start,
                                                   const int* __restrict__ counts,
                                                   const int2* __restrict__ csr,
                                                   const float* __restrict__ dinv,
                                                   const float* __restrict__ b2,
                                                   float* __restrict__ out, int n) {
    int wv = threadIdx.x >> 6;
    int i = blockIdx.x * 4 + wv;
    if (i >= n) return;
    int l = threadIdx.x & 63;
    int h = l >> 5, q = l & 31;
    bool act = q < 24;
    int qq = act ? q : 0;
    const ushort* rowp = h2b + 2 * qq;   // this lane's 2-feature slice

    float di = dinv[i];
    float sc = (h == 0 && act) ? di * di : 0.f;
    unsigned sv = *(const unsigned*)(rowp + (size_t)i * H2P);
    float2 acc;
    acc.x = sc * blo(sv); acc.y = sc * bhi(sv);

    int lo = row_start[i], hi = lo + ((counts[i] + 7) & ~7);
    for (int e = lo; e < hi; e += 8) {
        int2 pA = csr[e + 0 + h];
        int2 pB = csr[e + 2 + h];
        int2 pC = csr[e + 4 + h];
        int2 pD = csr[e + 6 + h];
        unsigned vA = *(const unsigned*)(rowp + (size_t)pA.x * H2P);
        unsigned vB = *(const unsigned*)(rowp + (size_t)pB.x * H2P);
        unsigned vC = *(const unsigned*)(rowp + (size_t)pC.x * H2P);
        unsigned vD = *(const unsigned*)(rowp + (size_t)pD.x * H2P);
        float wA = __int_as_float(pA.y), wB = __int_as_float(pB.y);
        float wC = __int_as_float(pC.y), wD = __int_as_float(pD.y);
        acc.x = fmaf(wA, blo(vA), acc.x); acc.y = fmaf(wA, bhi(vA), acc.y);
        acc.x = fmaf(wB, blo(vB), acc.x); acc.y = fmaf(wB, bhi(vB), acc.y);
        acc.x = fmaf(wC, blo(vC), acc.x); acc.y = fmaf(wC, bhi(vC), acc.y);
        acc.x = fmaf(wD, blo(vD), acc.x); acc.y = fmaf(wD, bhi(vD), acc.y);
    }
    acc.x += __shfl_xor(acc.x, 32);
    acc.y += __shfl_xor(acc.y, 32);

    float v0 = -1e30f, v1 = -1e30f;
    if (act) {
        v0 = acc.x + b2[2 * q];
        v1 = (2 * q + 1 < NCLASS) ? (acc.y + b2[2 * q + 1]) : -1e30f;
    }
    float pm = fmaxf(v0, v1);
    #pragma unroll
    for (int off = 16; off; off >>= 1) pm = fmaxf(pm, __shfl_xor(pm, off));
    float ex = 0.f;
    if (act) {
        ex = __expf(v0 - pm);
        if (2 * q + 1 < NCLASS) ex += __expf(v1 - pm);
    }
    #pragma unroll
    for (int off = 16; off; off >>= 1) ex += __shfl_xor(ex, off);
    if (h == 0 && act) {
        float ls = pm + __logf(ex);
        out[(size_t)i * NCLASS + 2 * q] = v0 - ls;
        if (2 * q + 1 < NCLASS) out[(size_t)i * NCLASS + 2 * q + 1] = v1 - ls;
    }
}

// ---------------- launch ----------------

extern "C" void kernel_launch(void* const* d_in, const int* in_sizes, int n_in,
                              void* d_out, int out_size, void* d_ws, size_t ws_size,
                              hipStream_t stream) {
    const float* x  = (const float*)d_in[0];
    const int*   ei = (const int*)d_in[1];
    const float* ew = (const float*)d_in[2];
    const float* W1 = (const float*)d_in[3];
    const float* b1 = (const float*)d_in[4];
    const float* W2 = (const float*)d_in[5];
    const float* b2 = (const float*)d_in[6];
    float* out = (float*)d_out;

    const int* e_src = ei;
    const int* e_dst = ei + N_EDGES;

    char* p = (char*)d_ws;
    auto carve = [&](size_t bytes) { void* r = (void*)p; p += (bytes + 255) & ~(size_t)255; return r; };
    unsigned long long* packed8 = (unsigned long long*)carve((size_t)N_NODES * NSUB * 8);
    float*  dinv      = (float*) carve(N_NODES * 4);
    int*    counts    = (int*)   carve(N_NODES * 4);
    int*    row_start = (int*)   carve(N_NODES * 4);
    int*    sub_base  = (int*)   carve((size_t)N_NODES * NSUB * 4);
    int*    total     = (int*)   carve(4);
    int*    pos       = (int*)   carve((size_t)N_EDGES * 4);
    int2*   csr       = (int2*)  carve((size_t)CSR_MAX * 8);
    ushort* h1b       = (ushort*)carve((size_t)N_NODES * NHID * 2);
    ushort* haggb     = (ushort*)carve((size_t)N_NODES * NHID * 2);
    ushort* h2b       = (ushort*)carve((size_t)N_NODES * H2P * 2);
    ushort* w1t       = (ushort*)carve((size_t)NHID * NFEAT * 2);
    ushort* w2t       = (ushort*)carve((size_t)H2P * NHID * 2);

    wprep_kernel<<<(NFEAT * NHID + 255) / 256, 256, 0, stream>>>(W1, W2, w1t, w2t);
    zero_init_kernel<<<(CSR_MAX + 255) / 256, 256, 0, stream>>>(packed8, csr, total);
    degcnt_kernel<<<(N_EDGES + 255) / 256, 256, 0, stream>>>(e_dst, ew, packed8, pos, N_EDGES);
    segalloc_kernel<<<(N_NODES + 255) / 256, 256, 0, stream>>>(packed8, counts, dinv,
                                                               row_start, sub_base, total, N_NODES);
    scatter_kernel<<<(N_EDGES + 255) / 256, 256, 0, stream>>>(e_src, e_dst, ew, pos, dinv,
                                                              row_start, sub_base, csr, N_EDGES);
    gemm1_kernel<<<(N_NODES + 63) / 64, 256, 0, stream>>>(x, w1t, h1b);
    {
        int chunks = (N_NODES + 4 * AG1_NPW - 1) / (4 * AG1_NPW);
        agg1_kernel<<<chunks * 8, 256, 0, stream>>>(h1b, row_start, counts, csr, dinv, b1, haggb);
    }
    gemm2_kernel<<<(N_NODES + 63) / 64, 256, 0, stream>>>(haggb, w2t, h2b);
    agg2_kernel<<<(N_NODES + 3) / 4, 256, 0, stream>>>(h2b, row_start, counts, csr, dinv, b2, out, N_NODES);
}

// Round 10
// 199.548 us; speedup vs baseline: 1.1511x; 1.1511x over previous
//
#include <hip/hip_runtime.h>

#define N_NODES 50000
#define N_EDGES 800000
#define NFEAT   256
#define NHID    128
#define NCLASS  47
#define H2P     48    // padded h2 row (bf16)
#define CSR_MAX (N_EDGES + 7 * N_NODES)   // every segment padded to multiple of 8
#define NSUB    8     // sub-bucketed degree counters (contention / NSUB)
#define AG1_SLICES 4
#define AG1_SF     32   // feats per slice: 64B rows = full cache lines

typedef __attribute__((ext_vector_type(8))) short short8v;
typedef __attribute__((ext_vector_type(4))) float f32x4;

__device__ __forceinline__ ushort f2bf(float f) {
    unsigned u = __float_as_uint(f);
    unsigned r = (u + 0x7FFF + ((u >> 16) & 1)) >> 16;   // round-to-nearest-even
    return (ushort)r;
}
__device__ __forceinline__ float bf2f(ushort b) {
    return __uint_as_float(((unsigned)b) << 16);
}
__device__ __forceinline__ float blo(unsigned u) { return __uint_as_float(u << 16); }
__device__ __forceinline__ float bhi(unsigned u) { return __uint_as_float(u & 0xFFFF0000u); }

// ---------------- weight prep: transpose+convert W1, W2 to bf16 once ----------------

__global__ void wprep_kernel(const float* __restrict__ W1, const float* __restrict__ W2,
                             ushort* __restrict__ w1t, ushort* __restrict__ w2t) {
    int t = blockIdx.x * blockDim.x + threadIdx.x;
    if (t < NFEAT * NHID) {              // read coalesced over c-fast
        int k = t >> 7, c = t & 127;
        w1t[c * NFEAT + k] = f2bf(W1[(size_t)k * NHID + c]);
    }
    if (t < NHID * H2P) {
        int k = t / H2P, c = t % H2P;
        w2t[c * NHID + k] = (c < NCLASS) ? f2bf(W2[(size_t)k * NCLASS + c]) : 0;
    }
}

// ---------------- CSR build ----------------

__global__ void zero_init_kernel(unsigned long long* __restrict__ packed8,
                                 int2* __restrict__ csr, int* __restrict__ total) {
    int i = blockIdx.x * blockDim.x + threadIdx.x;
    if (i < CSR_MAX) csr[i] = make_int2(0, 0);   // src=0, w=+0.0f (pad entries)
    if (i < N_NODES * NSUB) packed8[i] = 0ull;
    if (i == 0) *total = 0;
}

__global__ void degcnt_kernel(const int* __restrict__ dst, const float* __restrict__ w,
                              unsigned long long* __restrict__ packed8,
                              int* __restrict__ pos, int E) {
    int e = blockIdx.x * blockDim.x + threadIdx.x;
    if (e >= E) return;
    int d = dst[e];
    int b = e & (NSUB - 1);
    unsigned fx = __float2uint_rn(w[e] * 1048576.0f);
    unsigned long long old = atomicAdd(&packed8[(size_t)d * NSUB + b],
                                       (1ull << 40) | (unsigned long long)fx);
    pos[e] = (int)(old >> 40);
}

__global__ __launch_bounds__(256) void segalloc_kernel(const unsigned long long* __restrict__ packed8,
                                                       int* __restrict__ counts,
                                                       float* __restrict__ dinv,
                                                       int* __restrict__ row_start,
                                                       int* __restrict__ sub_base,
                                                       int* __restrict__ total, int n) {
    __shared__ int s[256];
    __shared__ int base_s;
    int t = threadIdx.x;
    int i = blockIdx.x * 256 + t;
    int v = 0;
    if (i < n) {
        int cnt = 0;
        unsigned long long ws = 0;
        int sb[NSUB];
        #pragma unroll
        for (int b = 0; b < NSUB; ++b) {
            unsigned long long pk = packed8[(size_t)i * NSUB + b];
            sb[b] = cnt;
            cnt += (int)(pk >> 40);
            ws += (pk & 0xFFFFFFFFFFull);
        }
        counts[i] = cnt;
        float deg = 1.0f + (float)ws * (1.0f / 1048576.0f);
        dinv[i] = rsqrtf(deg);
        #pragma unroll
        for (int b = 0; b < NSUB; b += 4)
            *(int4*)&sub_base[(size_t)i * NSUB + b] = make_int4(sb[b], sb[b+1], sb[b+2], sb[b+3]);
        v = (cnt + 7) & ~7;
    }
    s[t] = v;
    __syncthreads();
    #pragma unroll
    for (int off = 1; off < 256; off <<= 1) {
        int x = s[t];
        if (t >= off) x += s[t - off];
        __syncthreads();
        s[t] = x;
        __syncthreads();
    }
    if (t == 255) base_s = atomicAdd(total, s[255]);
    __syncthreads();
    if (i < n) row_start[i] = base_s + s[t] - v;
}

__global__ void scatter_kernel(const int* __restrict__ src, const int* __restrict__ dst,
                               const float* __restrict__ w, const int* __restrict__ pos,
                               const float* __restrict__ dinv,
                               const int* __restrict__ row_start,
                               const int* __restrict__ sub_base,
                               int2* __restrict__ csr, int E) {
    int e = blockIdx.x * blockDim.x + threadIdx.x;
    if (e >= E) return;
    int d = dst[e], s = src[e];
    int b = e & (NSUB - 1);
    int p = row_start[d] + sub_base[(size_t)d * NSUB + b] + pos[e];
    int2 pr;
    pr.x = s;
    pr.y = __float_as_int(dinv[s] * w[e] * dinv[d]);
    csr[p] = pr;
}

// ---------------- Layer 1 GEMM (MFMA bf16): h1b = bf16(x @ W1) ----------------

__global__ __launch_bounds__(256) void gemm1_kernel(const float* __restrict__ x,
                                                    const ushort* __restrict__ w1t,
                                                    ushort* __restrict__ h1b) {
    __shared__ __align__(16) ushort xs[64][72];
    __shared__ __align__(16) ushort ws[128][72];
    int tid = threadIdx.x;
    int node0 = blockIdx.x * 64;
    int wave = tid >> 6, l = tid & 63;
    int fr = l & 15, fq = l >> 4;
    int r0 = (wave >> 1) * 32;
    int c0 = (wave & 1) * 64;

    f32x4 acc[2][4] = {};

    for (int kk0 = 0; kk0 < NFEAT; kk0 += 64) {
        {
            int row = tid >> 2, q = tid & 3;
            int srow = node0 + row; if (srow >= N_NODES) srow = N_NODES - 1;
            const float4* src = (const float4*)(x + (size_t)srow * NFEAT + kk0 + q * 16);
            ushort tmp[16];
            #pragma unroll
            for (int i = 0; i < 4; ++i) {
                float4 v = src[i];
                tmp[i * 4 + 0] = f2bf(v.x); tmp[i * 4 + 1] = f2bf(v.y);
                tmp[i * 4 + 2] = f2bf(v.z); tmp[i * 4 + 3] = f2bf(v.w);
            }
            #pragma unroll
            for (int i = 0; i < 2; ++i)
                *(short8v*)&xs[row][q * 16 + i * 8] = *(short8v*)&tmp[i * 8];
        }
        {
            int rr = tid >> 3;
            int cq = tid & 7;
            #pragma unroll
            for (int i = 0; i < 4; ++i) {
                int row = rr + i * 32;
                *(short8v*)&ws[row][cq * 8] =
                    *(const short8v*)&w1t[(size_t)row * NFEAT + kk0 + cq * 8];
            }
        }
        __syncthreads();
        short8v a[2][2], b[4][2];
        #pragma unroll
        for (int m = 0; m < 2; ++m)
            #pragma unroll
            for (int kf = 0; kf < 2; ++kf)
                a[m][kf] = *(const short8v*)&xs[r0 + m * 16 + fr][kf * 32 + fq * 8];
        #pragma unroll
        for (int n = 0; n < 4; ++n)
            #pragma unroll
            for (int kf = 0; kf < 2; ++kf)
                b[n][kf] = *(const short8v*)&ws[c0 + n * 16 + fr][kf * 32 + fq * 8];
        #pragma unroll
        for (int m = 0; m < 2; ++m)
            #pragma unroll
            for (int n = 0; n < 4; ++n)
                #pragma unroll
                for (int kf = 0; kf < 2; ++kf)
                    acc[m][n] = __builtin_amdgcn_mfma_f32_16x16x32_bf16(
                        a[m][kf], b[n][kf], acc[m][n], 0, 0, 0);
        __syncthreads();
    }
    #pragma unroll
    for (int m = 0; m < 2; ++m) {
        #pragma unroll
        for (int n = 0; n < 4; ++n) {
            #pragma unroll
            for (int j = 0; j < 4; ++j) {
                int gr = node0 + r0 + m * 16 + fq * 4 + j;
                if (gr < N_NODES)
                    h1b[(size_t)gr * NHID + c0 + n * 16 + fr] = f2bf(acc[m][n][j]);
            }
        }
    }
}

// ---------------- Aggregation 1 (4 slices x 32 feats, contiguous-chunk phases) ----------
// slice = blockIdx / 12500: blocks dispatch roughly in order, so at any instant all
// XCDs work on the same 3.2 MB (L2-resident) slice; rows are full 64B lines.
// Lane: eg = lane>>3 (8 edge-groups), fp = lane&7 (4 feats via uint2). One wave-load
// gathers 8 edges x 64B. 16-edge unroll keeps 2 chains in flight.

__global__ __launch_bounds__(256) void agg1_kernel(const ushort* __restrict__ h1b,
                                                   const int* __restrict__ row_start,
                                                   const int* __restrict__ counts,
                                                   const int2* __restrict__ csr,
                                                   const float* __restrict__ dinv,
                                                   const float* __restrict__ b1,
                                                   ushort* __restrict__ haggb) {
    const int nbps = (N_NODES + 3) / 4;            // blocks per slice
    int slice = blockIdx.x / nbps;
    int blk   = blockIdx.x % nbps;
    int wv = threadIdx.x >> 6, l = threadIdx.x & 63;
    int eg = l >> 3, fp = l & 7;
    int f0 = slice * AG1_SF + fp * 4;
    const ushort* rowp = h1b + f0;
    int i = blk * 4 + wv;
    if (i >= N_NODES) return;

    float di = dinv[i];
    float sc = (eg == 0) ? di * di : 0.f;
    uint2 sv = *(const uint2*)(rowp + (size_t)i * NHID);
    float4 acc;
    acc.x = sc * blo(sv.x); acc.y = sc * bhi(sv.x);
    acc.z = sc * blo(sv.y); acc.w = sc * bhi(sv.y);

    int lo = row_start[i], hi = lo + ((counts[i] + 7) & ~7);
    int e = lo;
    for (; e + 16 <= hi; e += 16) {
        int2 p1 = csr[e + eg];
        int2 p2 = csr[e + 8 + eg];
        uint2 v1 = *(const uint2*)(rowp + (size_t)p1.x * NHID);
        uint2 v2 = *(const uint2*)(rowp + (size_t)p2.x * NHID);
        float w1 = __int_as_float(p1.y), w2 = __int_as_float(p2.y);
        acc.x = fmaf(w1, blo(v1.x), acc.x); acc.y = fmaf(w1, bhi(v1.x), acc.y);
        acc.z = fmaf(w1, blo(v1.y), acc.z); acc.w = fmaf(w1, bhi(v1.y), acc.w);
        acc.x = fmaf(w2, blo(v2.x), acc.x); acc.y = fmaf(w2, bhi(v2.x), acc.y);
        acc.z = fmaf(w2, blo(v2.y), acc.z); acc.w = fmaf(w2, bhi(v2.y), acc.w);
    }
    if (e < hi) {
        int2 p1 = csr[e + eg];
        uint2 v1 = *(const uint2*)(rowp + (size_t)p1.x * NHID);
        float w1 = __int_as_float(p1.y);
        acc.x = fmaf(w1, blo(v1.x), acc.x); acc.y = fmaf(w1, bhi(v1.x), acc.y);
        acc.z = fmaf(w1, blo(v1.y), acc.z); acc.w = fmaf(w1, bhi(v1.y), acc.w);
    }
    // reduce across the 8 edge-groups (lane bits 3,4,5)
    #pragma unroll
    for (int off = 8; off <= 32; off <<= 1) {
        acc.x += __shfl_xor(acc.x, off);
        acc.y += __shfl_xor(acc.y, off);
        acc.z += __shfl_xor(acc.z, off);
        acc.w += __shfl_xor(acc.w, off);
    }
    if (eg == 0) {
        float4 bb = *(const float4*)(b1 + f0);
        acc.x = fmaxf(acc.x + bb.x, 0.f);
        acc.y = fmaxf(acc.y + bb.y, 0.f);
        acc.z = fmaxf(acc.z + bb.z, 0.f);
        acc.w = fmaxf(acc.w + bb.w, 0.f);
        uint2 o;
        o.x = (unsigned)f2bf(acc.x) | ((unsigned)f2bf(acc.y) << 16);
        o.y = (unsigned)f2bf(acc.z) | ((unsigned)f2bf(acc.w) << 16);
        *(uint2*)(haggb + (size_t)i * NHID + f0) = o;
    }
}

// ---------------- Layer 2 GEMM (MFMA bf16): h2b = bf16(hagg @ W2), rows padded to 48 ----------------

__global__ __launch_bounds__(256) void gemm2_kernel(const ushort* __restrict__ haggb,
                                                    const ushort* __restrict__ w2t,
                                                    ushort* __restrict__ h2b) {
    __shared__ __align__(16) ushort ha[64][136];
    __shared__ __align__(16) ushort wt[48][136];
    int tid = threadIdx.x;
    int node0 = blockIdx.x * 64;
    {
        int row = tid >> 2, q = tid & 3;
        int srow = node0 + row; if (srow >= N_NODES) srow = N_NODES - 1;
        const short8v* src = (const short8v*)(haggb + (size_t)srow * NHID + q * 32);
        #pragma unroll
        for (int i = 0; i < 4; ++i)
            *(short8v*)&ha[row][q * 32 + i * 8] = src[i];
    }
    {
        #pragma unroll
        for (int i = 0; i < 3; ++i) {
            int id = tid + i * 256;
            int row = id >> 4, cq = id & 15;
            *(short8v*)&wt[row][cq * 8] =
                *(const short8v*)&w2t[(size_t)row * NHID + cq * 8];
        }
    }
    __syncthreads();
    int wave = tid >> 6, l = tid & 63;
    int fr = l & 15, fq = l >> 4;
    int r0 = wave * 16;
    short8v a[4], b[3][4];
    #pragma unroll
    for (int kf = 0; kf < 4; ++kf)
        a[kf] = *(const short8v*)&ha[r0 + fr][kf * 32 + fq * 8];
    #pragma unroll
    for (int n = 0; n < 3; ++n)
        #pragma unroll
        for (int kf = 0; kf < 4; ++kf)
            b[n][kf] = *(const short8v*)&wt[n * 16 + fr][kf * 32 + fq * 8];
    f32x4 acc[3] = {};
    #pragma unroll
    for (int n = 0; n < 3; ++n)
        #pragma unroll
        for (int kf = 0; kf < 4; ++kf)
            acc[n] = __builtin_amdgcn_mfma_f32_16x16x32_bf16(a[kf], b[n][kf], acc[n], 0, 0, 0);
    #pragma unroll
    for (int n = 0; n < 3; ++n) {
        #pragma unroll
        for (int j = 0; j < 4; ++j) {
            int gr = node0 + r0 + fq * 4 + j;
            int col = n * 16 + fr;
            if (gr < N_NODES && col < H2P)
                h2b[(size_t)gr * H2P + col] = (col < NCLASS) ? f2bf(acc[n][j]) : 0;
        }
    }
}

// ---------------- Aggregation 2 + bias + log_softmax -> out ----------------

__global__ __launch_bounds__(256) void agg2_kernel(const ushort* __restrict__ h2b,
                                                   const int* __restrict__ row_start,
                                                   const int* __restrict__ counts,
                                                   const int2* __restrict__ csr,
                                                   const float* __restrict__ dinv,
                                                   const float* __restrict__ b2,
                                                   float* __restrict__ out, int n) {
    int wv = threadIdx.x >> 6;
    int i = blockIdx.x * 4 + wv;
    if (i >= n) return;
    int l = threadIdx.x & 63;
    int h = l >> 5, q = l & 31;
    bool act = q < 24;
    int qq = act ? q : 0;
    const ushort* rowp = h2b + 2 * qq;   // this lane's 2-feature slice

    float di = dinv[i];
    float sc = (h == 0 && act) ? di * di : 0.f;
    unsigned sv = *(const unsigned*)(rowp + (size_t)i * H2P);
    float2 acc;
    acc.x = sc * blo(sv); acc.y = sc * bhi(sv);

    int lo = row_start[i], hi = lo + ((counts[i] + 7) & ~7);
    for (int e = lo; e < hi; e += 8) {
        int2 pA = csr[e + 0 + h];
        int2 pB = csr[e + 2 + h];
        int2 pC = csr[e + 4 + h];
        int2 pD = csr[e + 6 + h];
        unsigned vA = *(const unsigned*)(rowp + (size_t)pA.x * H2P);
        unsigned vB = *(const unsigned*)(rowp + (size_t)pB.x * H2P);
        unsigned vC = *(const unsigned*)(rowp + (size_t)pC.x * H2P);
        unsigned vD = *(const unsigned*)(rowp + (size_t)pD.x * H2P);
        float wA = __int_as_float(pA.y), wB = __int_as_float(pB.y);
        float wC = __int_as_float(pC.y), wD = __int_as_float(pD.y);
        acc.x = fmaf(wA, blo(vA), acc.x); acc.y = fmaf(wA, bhi(vA), acc.y);
        acc.x = fmaf(wB, blo(vB), acc.x); acc.y = fmaf(wB, bhi(vB), acc.y);
        acc.x = fmaf(wC, blo(vC), acc.x); acc.y = fmaf(wC, bhi(vC), acc.y);
        acc.x = fmaf(wD, blo(vD), acc.x); acc.y = fmaf(wD, bhi(vD), acc.y);
    }
    acc.x += __shfl_xor(acc.x, 32);
    acc.y += __shfl_xor(acc.y, 32);

    float v0 = -1e30f, v1 = -1e30f;
    if (act) {
        v0 = acc.x + b2[2 * q];
        v1 = (2 * q + 1 < NCLASS) ? (acc.y + b2[2 * q + 1]) : -1e30f;
    }
    float pm = fmaxf(v0, v1);
    #pragma unroll
    for (int off = 16; off; off >>= 1) pm = fmaxf(pm, __shfl_xor(pm, off));
    float ex = 0.f;
    if (act) {
        ex = __expf(v0 - pm);
        if (2 * q + 1 < NCLASS) ex += __expf(v1 - pm);
    }
    #pragma unroll
    for (int off = 16; off; off >>= 1) ex += __shfl_xor(ex, off);
    if (h == 0 && act) {
        float ls = pm + __logf(ex);
        out[(size_t)i * NCLASS + 2 * q] = v0 - ls;
        if (2 * q + 1 < NCLASS) out[(size_t)i * NCLASS + 2 * q + 1] = v1 - ls;
    }
}

// ---------------- launch ----------------

extern "C" void kernel_launch(void* const* d_in, const int* in_sizes, int n_in,
                              void* d_out, int out_size, void* d_ws, size_t ws_size,
                              hipStream_t stream) {
    const float* x  = (const float*)d_in[0];
    const int*   ei = (const int*)d_in[1];
    const float* ew = (const float*)d_in[2];
    const float* W1 = (const float*)d_in[3];
    const float* b1 = (const float*)d_in[4];
    const float* W2 = (const float*)d_in[5];
    const float* b2 = (const float*)d_in[6];
    float* out = (float*)d_out;

    const int* e_src = ei;
    const int* e_dst = ei + N_EDGES;

    char* p = (char*)d_ws;
    auto carve = [&](size_t bytes) { void* r = (void*)p; p += (bytes + 255) & ~(size_t)255; return r; };
    unsigned long long* packed8 = (unsigned long long*)carve((size_t)N_NODES * NSUB * 8);
    float*  dinv      = (float*) carve(N_NODES * 4);
    int*    counts    = (int*)   carve(N_NODES * 4);
    int*    row_start = (int*)   carve(N_NODES * 4);
    int*    sub_base  = (int*)   carve((size_t)N_NODES * NSUB * 4);
    int*    total     = (int*)   carve(4);
    int*    pos       = (int*)   carve((size_t)N_EDGES * 4);
    int2*   csr       = (int2*)  carve((size_t)CSR_MAX * 8);
    ushort* h1b       = (ushort*)carve((size_t)N_NODES * NHID * 2);
    ushort* haggb     = (ushort*)carve((size_t)N_NODES * NHID * 2);
    ushort* h2b       = (ushort*)carve((size_t)N_NODES * H2P * 2);
    ushort* w1t       = (ushort*)carve((size_t)NHID * NFEAT * 2);
    ushort* w2t       = (ushort*)carve((size_t)H2P * NHID * 2);

    wprep_kernel<<<(NFEAT * NHID + 255) / 256, 256, 0, stream>>>(W1, W2, w1t, w2t);
    zero_init_kernel<<<(CSR_MAX + 255) / 256, 256, 0, stream>>>(packed8, csr, total);
    degcnt_kernel<<<(N_EDGES + 255) / 256, 256, 0, stream>>>(e_dst, ew, packed8, pos, N_EDGES);
    segalloc_kernel<<<(N_NODES + 255) / 256, 256, 0, stream>>>(packed8, counts, dinv,
                                                               row_start, sub_base, total, N_NODES);
    scatter_kernel<<<(N_EDGES + 255) / 256, 256, 0, stream>>>(e_src, e_dst, ew, pos, dinv,
                                                              row_start, sub_base, csr, N_EDGES);
    gemm1_kernel<<<(N_NODES + 63) / 64, 256, 0, stream>>>(x, w1t, h1b);
    {
        int nbps = (N_NODES + 3) / 4;
        agg1_kernel<<<nbps * AG1_SLICES, 256, 0, stream>>>(h1b, row_start, counts, csr,
                                                           dinv, b1, haggb);
    }
    gemm2_kernel<<<(N_NODES + 63) / 64, 256, 0, stream>>>(haggb, w2t, h2b);
    agg2_kernel<<<(N_NODES + 3) / 4, 256, 0, stream>>>(h2b, row_start, counts, csr, dinv, b2, out, N_NODES);
}

// Round 11
// 162.581 us; speedup vs baseline: 1.4128x; 1.2274x over previous
//
#include <hip/hip_runtime.h>

#define N_NODES 50000
#define N_EDGES 800000
#define NFEAT   256
#define NHID    128
#define NCLASS  47
#define H2P     48    // padded h2 row (bf16)
#define CSR_MAX (N_EDGES + 7 * N_NODES)   // every segment padded to multiple of 8
#define NSUB    16    // sub-bucketed degree counters (contention / NSUB)

typedef __attribute__((ext_vector_type(8))) short short8v;
typedef __attribute__((ext_vector_type(4))) float f32x4;

__device__ __forceinline__ ushort f2bf(float f) {
    unsigned u = __float_as_uint(f);
    unsigned r = (u + 0x7FFF + ((u >> 16) & 1)) >> 16;   // round-to-nearest-even
    return (ushort)r;
}
__device__ __forceinline__ float bf2f(ushort b) {
    return __uint_as_float(((unsigned)b) << 16);
}
__device__ __forceinline__ float blo(unsigned u) { return __uint_as_float(u << 16); }
__device__ __forceinline__ float bhi(unsigned u) { return __uint_as_float(u & 0xFFFF0000u); }

// ------- init: zero packed counters + total, and prep bf16 transposed weights -------

__global__ void init_kernel(unsigned long long* __restrict__ packed,
                            int* __restrict__ total,
                            const float* __restrict__ W1, const float* __restrict__ W2,
                            ushort* __restrict__ w1t, ushort* __restrict__ w2t) {
    int t = blockIdx.x * blockDim.x + threadIdx.x;
    if (t < N_NODES * NSUB) packed[t] = 0ull;
    if (t == 0) *total = 0;
    if (t < NFEAT * NHID) {              // read coalesced over c-fast
        int k = t >> 7, c = t & 127;
        w1t[c * NFEAT + k] = f2bf(W1[(size_t)k * NHID + c]);
    }
    if (t < NHID * H2P) {
        int k = t / H2P, c = t % H2P;
        w2t[c * NHID + k] = (c < NCLASS) ? f2bf(W2[(size_t)k * NCLASS + c]) : 0;
    }
}

// ---------------- CSR build ----------------
// packed[d*16+b]: high 24 bits = count, low 40 bits = sum(w) in 2^-20 fixed point.
// One 64-bit atomic per edge; returned old count doubles as the CSR slot index.

__global__ void degcnt_kernel(const int* __restrict__ dst, const float* __restrict__ w,
                              unsigned long long* __restrict__ packed,
                              int* __restrict__ pos, int E) {
    int e = blockIdx.x * blockDim.x + threadIdx.x;
    if (e >= E) return;
    int d = dst[e];
    int b = e & (NSUB - 1);
    unsigned fx = __float2uint_rn(w[e] * 1048576.0f);
    unsigned long long old = atomicAdd(&packed[(size_t)d * NSUB + b],
                                       (1ull << 40) | (unsigned long long)fx);
    pos[e] = (int)(old >> 40);
}

// segment allocator + dinv + pad-writer: block-local scan + one atomicAdd per block.
// Segments padded to multiple of 8; the pad entries (src=0,w=0) are written HERE,
// so no separate csr zero-fill pass is needed.
__global__ __launch_bounds__(256) void segalloc_kernel(const unsigned long long* __restrict__ packed,
                                                       int* __restrict__ counts,
                                                       float* __restrict__ dinv,
                                                       int* __restrict__ row_start,
                                                       int* __restrict__ sub_base,
                                                       int* __restrict__ total,
                                                       int2* __restrict__ csr, int n) {
    __shared__ int s[256];
    __shared__ int base_s;
    int t = threadIdx.x;
    int i = blockIdx.x * 256 + t;
    int v = 0, cnt = 0;
    if (i < n) {
        unsigned long long ws = 0;
        int sb[NSUB];
        #pragma unroll
        for (int b = 0; b < NSUB; ++b) {
            unsigned long long pk = packed[(size_t)i * NSUB + b];
            sb[b] = cnt;
            cnt += (int)(pk >> 40);
            ws += (pk & 0xFFFFFFFFFFull);
        }
        counts[i] = cnt;
        float deg = 1.0f + (float)ws * (1.0f / 1048576.0f);
        dinv[i] = rsqrtf(deg);
        #pragma unroll
        for (int b = 0; b < NSUB; b += 4)
            *(int4*)&sub_base[(size_t)i * NSUB + b] = make_int4(sb[b], sb[b+1], sb[b+2], sb[b+3]);
        v = (cnt + 7) & ~7;
    }
    s[t] = v;
    __syncthreads();
    #pragma unroll
    for (int off = 1; off < 256; off <<= 1) {
        int x = s[t];
        if (t >= off) x += s[t - off];
        __syncthreads();
        s[t] = x;
        __syncthreads();
    }
    if (t == 255) base_s = atomicAdd(total, s[255]);
    __syncthreads();
    if (i < n) {
        int base = base_s + s[t] - v;
        row_start[i] = base;
        for (int k = cnt; k < v; ++k) csr[base + k] = make_int2(0, 0);  // pads
    }
}

// atomic-free scatter: slot = row_start[d] + sub_base[d][b] + pos[e]
__global__ void scatter_kernel(const int* __restrict__ src, const int* __restrict__ dst,
                               const float* __restrict__ w, const int* __restrict__ pos,
                               const float* __restrict__ dinv,
                               const int* __restrict__ row_start,
                               const int* __restrict__ sub_base,
                               int2* __restrict__ csr, int E) {
    int e = blockIdx.x * blockDim.x + threadIdx.x;
    if (e >= E) return;
    int d = dst[e], s = src[e];
    int b = e & (NSUB - 1);
    int p = row_start[d] + sub_base[(size_t)d * NSUB + b] + pos[e];
    int2 pr;
    pr.x = s;
    pr.y = __float_as_int(dinv[s] * w[e] * dinv[d]);
    csr[p] = pr;
}

// ---------------- Layer 1 GEMM (MFMA bf16): h1b = bf16(x @ W1) ----------------

__global__ __launch_bounds__(256) void gemm1_kernel(const float* __restrict__ x,
                                                    const ushort* __restrict__ w1t,
                                                    ushort* __restrict__ h1b) {
    __shared__ __align__(16) ushort xs[64][72];
    __shared__ __align__(16) ushort ws[128][72];
    int tid = threadIdx.x;
    int node0 = blockIdx.x * 64;
    int wave = tid >> 6, l = tid & 63;
    int fr = l & 15, fq = l >> 4;
    int r0 = (wave >> 1) * 32;
    int c0 = (wave & 1) * 64;

    f32x4 acc[2][4] = {};

    for (int kk0 = 0; kk0 < NFEAT; kk0 += 64) {
        {
            int row = tid >> 2, q = tid & 3;
            int srow = node0 + row; if (srow >= N_NODES) srow = N_NODES - 1;
            const float4* src = (const float4*)(x + (size_t)srow * NFEAT + kk0 + q * 16);
            ushort tmp[16];
            #pragma unroll
            for (int i = 0; i < 4; ++i) {
                float4 v = src[i];
                tmp[i * 4 + 0] = f2bf(v.x); tmp[i * 4 + 1] = f2bf(v.y);
                tmp[i * 4 + 2] = f2bf(v.z); tmp[i * 4 + 3] = f2bf(v.w);
            }
            #pragma unroll
            for (int i = 0; i < 2; ++i)
                *(short8v*)&xs[row][q * 16 + i * 8] = *(short8v*)&tmp[i * 8];
        }
        {
            int rr = tid >> 3;
            int cq = tid & 7;
            #pragma unroll
            for (int i = 0; i < 4; ++i) {
                int row = rr + i * 32;
                *(short8v*)&ws[row][cq * 8] =
                    *(const short8v*)&w1t[(size_t)row * NFEAT + kk0 + cq * 8];
            }
        }
        __syncthreads();
        short8v a[2][2], b[4][2];
        #pragma unroll
        for (int m = 0; m < 2; ++m)
            #pragma unroll
            for (int kf = 0; kf < 2; ++kf)
                a[m][kf] = *(const short8v*)&xs[r0 + m * 16 + fr][kf * 32 + fq * 8];
        #pragma unroll
        for (int n = 0; n < 4; ++n)
            #pragma unroll
            for (int kf = 0; kf < 2; ++kf)
                b[n][kf] = *(const short8v*)&ws[c0 + n * 16 + fr][kf * 32 + fq * 8];
        #pragma unroll
        for (int m = 0; m < 2; ++m)
            #pragma unroll
            for (int n = 0; n < 4; ++n)
                #pragma unroll
                for (int kf = 0; kf < 2; ++kf)
                    acc[m][n] = __builtin_amdgcn_mfma_f32_16x16x32_bf16(
                        a[m][kf], b[n][kf], acc[m][n], 0, 0, 0);
        __syncthreads();
    }
    #pragma unroll
    for (int m = 0; m < 2; ++m) {
        #pragma unroll
        for (int n = 0; n < 4; ++n) {
            #pragma unroll
            for (int j = 0; j < 4; ++j) {
                int gr = node0 + r0 + m * 16 + fq * 4 + j;
                if (gr < N_NODES)
                    h1b[(size_t)gr * NHID + c0 + n * 16 + fr] = f2bf(acc[m][n][j]);
            }
        }
    }
}

// ---------------- Aggregation 1: haggb = bf16(relu(A_norm @ h1 + b1)) ----------------
// one WAVE per node (r8 structure, 16-edge unroll); lane=(half h, quarter q);
// each lane gathers 8B (4 feats); two halves process 2 edges/instr; 16 edges/iter.

__global__ __launch_bounds__(256) void agg1_kernel(const ushort* __restrict__ h1b,
                                                   const int* __restrict__ row_start,
                                                   const int* __restrict__ counts,
                                                   const int2* __restrict__ csr,
                                                   const float* __restrict__ dinv,
                                                   const float* __restrict__ b1,
                                                   ushort* __restrict__ haggb) {
    int wv = threadIdx.x >> 6;
    int i = blockIdx.x * 4 + wv;
    int l = threadIdx.x & 63;
    int h = l >> 5, q = l & 31;
    const ushort* rowp = h1b + 4 * q;    // this lane's 4-feature slice

    float di = dinv[i];
    float sc = (h == 0) ? di * di : 0.f;
    uint2 sv = *(const uint2*)(rowp + (size_t)i * NHID);
    float4 acc;
    acc.x = sc * blo(sv.x); acc.y = sc * bhi(sv.x);
    acc.z = sc * blo(sv.y); acc.w = sc * bhi(sv.y);

    int lo = row_start[i], hi = lo + ((counts[i] + 7) & ~7);
    int e = lo;
    for (; e + 16 <= hi; e += 16) {
        int2 pA = csr[e + 0 + h],  pB = csr[e + 2 + h];
        int2 pC = csr[e + 4 + h],  pD = csr[e + 6 + h];
        int2 pE = csr[e + 8 + h],  pF = csr[e + 10 + h];
        int2 pG = csr[e + 12 + h], pH = csr[e + 14 + h];
        uint2 vA = *(const uint2*)(rowp + (size_t)pA.x * NHID);
        uint2 vB = *(const uint2*)(rowp + (size_t)pB.x * NHID);
        uint2 vC = *(const uint2*)(rowp + (size_t)pC.x * NHID);
        uint2 vD = *(const uint2*)(rowp + (size_t)pD.x * NHID);
        uint2 vE = *(const uint2*)(rowp + (size_t)pE.x * NHID);
        uint2 vF = *(const uint2*)(rowp + (size_t)pF.x * NHID);
        uint2 vG = *(const uint2*)(rowp + (size_t)pG.x * NHID);
        uint2 vH = *(const uint2*)(rowp + (size_t)pH.x * NHID);
        float wA = __int_as_float(pA.y), wB = __int_as_float(pB.y);
        float wC = __int_as_float(pC.y), wD = __int_as_float(pD.y);
        float wE = __int_as_float(pE.y), wF = __int_as_float(pF.y);
        float wG = __int_as_float(pG.y), wH = __int_as_float(pH.y);
        acc.x = fmaf(wA, blo(vA.x), acc.x); acc.y = fmaf(wA, bhi(vA.x), acc.y);
        acc.z = fmaf(wA, blo(vA.y), acc.z); acc.w = fmaf(wA, bhi(vA.y), acc.w);
        acc.x = fmaf(wB, blo(vB.x), acc.x); acc.y = fmaf(wB, bhi(vB.x), acc.y);
        acc.z = fmaf(wB, blo(vB.y), acc.z); acc.w = fmaf(wB, bhi(vB.y), acc.w);
        acc.x = fmaf(wC, blo(vC.x), acc.x); acc.y = fmaf(wC, bhi(vC.x), acc.y);
        acc.z = fmaf(wC, blo(vC.y), acc.z); acc.w = fmaf(wC, bhi(vC.y), acc.w);
        acc.x = fmaf(wD, blo(vD.x), acc.x); acc.y = fmaf(wD, bhi(vD.x), acc.y);
        acc.z = fmaf(wD, blo(vD.y), acc.z); acc.w = fmaf(wD, bhi(vD.y), acc.w);
        acc.x = fmaf(wE, blo(vE.x), acc.x); acc.y = fmaf(wE, bhi(vE.x), acc.y);
        acc.z = fmaf(wE, blo(vE.y), acc.z); acc.w = fmaf(wE, bhi(vE.y), acc.w);
        acc.x = fmaf(wF, blo(vF.x), acc.x); acc.y = fmaf(wF, bhi(vF.x), acc.y);
        acc.z = fmaf(wF, blo(vF.y), acc.z); acc.w = fmaf(wF, bhi(vF.y), acc.w);
        acc.x = fmaf(wG, blo(vG.x), acc.x); acc.y = fmaf(wG, bhi(vG.x), acc.y);
        acc.z = fmaf(wG, blo(vG.y), acc.z); acc.w = fmaf(wG, bhi(vG.y), acc.w);
        acc.x = fmaf(wH, blo(vH.x), acc.x); acc.y = fmaf(wH, bhi(vH.x), acc.y);
        acc.z = fmaf(wH, blo(vH.y), acc.z); acc.w = fmaf(wH, bhi(vH.y), acc.w);
    }
    if (e < hi) {   // one remaining 8-edge group
        int2 pA = csr[e + 0 + h], pB = csr[e + 2 + h];
        int2 pC = csr[e + 4 + h], pD = csr[e + 6 + h];
        uint2 vA = *(const uint2*)(rowp + (size_t)pA.x * NHID);
        uint2 vB = *(const uint2*)(rowp + (size_t)pB.x * NHID);
        uint2 vC = *(const uint2*)(rowp + (size_t)pC.x * NHID);
        uint2 vD = *(const uint2*)(rowp + (size_t)pD.x * NHID);
        float wA = __int_as_float(pA.y), wB = __int_as_float(pB.y);
        float wC = __int_as_float(pC.y), wD = __int_as_float(pD.y);
        acc.x = fmaf(wA, blo(vA.x), acc.x); acc.y = fmaf(wA, bhi(vA.x), acc.y);
        acc.z = fmaf(wA, blo(vA.y), acc.z); acc.w = fmaf(wA, bhi(vA.y), acc.w);
        acc.x = fmaf(wB, blo(vB.x), acc.x); acc.y = fmaf(wB, bhi(vB.x), acc.y);
        acc.z = fmaf(wB, blo(vB.y), acc.z); acc.w = fmaf(wB, bhi(vB.y), acc.w);
        acc.x = fmaf(wC, blo(vC.x), acc.x); acc.y = fmaf(wC, bhi(vC.x), acc.y);
        acc.z = fmaf(wC, blo(vC.y), acc.z); acc.w = fmaf(wC, bhi(vC.y), acc.w);
        acc.x = fmaf(wD, blo(vD.x), acc.x); acc.y = fmaf(wD, bhi(vD.x), acc.y);
        acc.z = fmaf(wD, blo(vD.y), acc.z); acc.w = fmaf(wD, bhi(vD.y), acc.w);
    }
    acc.x += __shfl_xor(acc.x, 32);
    acc.y += __shfl_xor(acc.y, 32);
    acc.z += __shfl_xor(acc.z, 32);
    acc.w += __shfl_xor(acc.w, 32);
    if (h == 0) {
        float4 bb = *(const float4*)(b1 + 4 * q);
        acc.x = fmaxf(acc.x + bb.x, 0.f);
        acc.y = fmaxf(acc.y + bb.y, 0.f);
        acc.z = fmaxf(acc.z + bb.z, 0.f);
        acc.w = fmaxf(acc.w + bb.w, 0.f);
        uint2 o;
        o.x = (unsigned)f2bf(acc.x) | ((unsigned)f2bf(acc.y) << 16);
        o.y = (unsigned)f2bf(acc.z) | ((unsigned)f2bf(acc.w) << 16);
        *(uint2*)(haggb + (size_t)i * NHID + 4 * q) = o;
    }
}

// ---------------- Layer 2 GEMM (MFMA bf16): h2b = bf16(hagg @ W2), rows padded to 48 ----------------

__global__ __launch_bounds__(256) void gemm2_kernel(const ushort* __restrict__ haggb,
                                                    const ushort* __restrict__ w2t,
                                                    ushort* __restrict__ h2b) {
    __shared__ __align__(16) ushort ha[64][136];
    __shared__ __align__(16) ushort wt[48][136];
    int tid = threadIdx.x;
    int node0 = blockIdx.x * 64;
    {
        int row = tid >> 2, q = tid & 3;
        int srow = node0 + row; if (srow >= N_NODES) srow = N_NODES - 1;
        const short8v* src = (const short8v*)(haggb + (size_t)srow * NHID + q * 32);
        #pragma unroll
        for (int i = 0; i < 4; ++i)
            *(short8v*)&ha[row][q * 32 + i * 8] = src[i];
    }
    {
        #pragma unroll
        for (int i = 0; i < 3; ++i) {
            int id = tid + i * 256;
            int row = id >> 4, cq = id & 15;
            *(short8v*)&wt[row][cq * 8] =
                *(const short8v*)&w2t[(size_t)row * NHID + cq * 8];
        }
    }
    __syncthreads();
    int wave = tid >> 6, l = tid & 63;
    int fr = l & 15, fq = l >> 4;
    int r0 = wave * 16;
    short8v a[4], b[3][4];
    #pragma unroll
    for (int kf = 0; kf < 4; ++kf)
        a[kf] = *(const short8v*)&ha[r0 + fr][kf * 32 + fq * 8];
    #pragma unroll
    for (int n = 0; n < 3; ++n)
        #pragma unroll
        for (int kf = 0; kf < 4; ++kf)
            b[n][kf] = *(const short8v*)&wt[n * 16 + fr][kf * 32 + fq * 8];
    f32x4 acc[3] = {};
    #pragma unroll
    for (int n = 0; n < 3; ++n)
        #pragma unroll
        for (int kf = 0; kf < 4; ++kf)
            acc[n] = __builtin_amdgcn_mfma_f32_16x16x32_bf16(a[kf], b[n][kf], acc[n], 0, 0, 0);
    #pragma unroll
    for (int n = 0; n < 3; ++n) {
        #pragma unroll
        for (int j = 0; j < 4; ++j) {
            int gr = node0 + r0 + fq * 4 + j;
            int col = n * 16 + fr;
            if (gr < N_NODES && col < H2P)
                h2b[(size_t)gr * H2P + col] = (col < NCLASS) ? f2bf(acc[n][j]) : 0;
        }
    }
}

// ---------------- Aggregation 2 + bias + log_softmax -> out ----------------
// one WAVE per node; lanes 0-23 / 32-55 each load 4B; 16-edge unrolled loop.

__global__ __launch_bounds__(256) void agg2_kernel(const ushort* __restrict__ h2b,
                                                   const int* __restrict__ row_start,
                                                   const int* __restrict__ counts,
                                                   const int2* __restrict__ csr,
                                                   const float* __restrict__ dinv,
                                                   const float* __restrict__ b2,
                                                   float* __restrict__ out, int n) {
    int wv = threadIdx.x >> 6;
    int i = blockIdx.x * 4 + wv;
    if (i >= n) return;
    int l = threadIdx.x & 63;
    int h = l >> 5, q = l & 31;
    bool act = q < 24;
    int qq = act ? q : 0;
    const ushort* rowp = h2b + 2 * qq;   // this lane's 2-feature slice

    float di = dinv[i];
    float sc = (h == 0 && act) ? di * di : 0.f;
    unsigned sv = *(const unsigned*)(rowp + (size_t)i * H2P);
    float2 acc;
    acc.x = sc * blo(sv); acc.y = sc * bhi(sv);

    int lo = row_start[i], hi = lo + ((counts[i] + 7) & ~7);
    int e = lo;
    for (; e + 16 <= hi; e += 16) {
        int2 pA = csr[e + 0 + h],  pB = csr[e + 2 + h];
        int2 pC = csr[e + 4 + h],  pD = csr[e + 6 + h];
        int2 pE = csr[e + 8 + h],  pF = csr[e + 10 + h];
        int2 pG = csr[e + 12 + h], pH = csr[e + 14 + h];
        unsigned vA = *(const unsigned*)(rowp + (size_t)pA.x * H2P);
        unsigned vB = *(const unsigned*)(rowp + (size_t)pB.x * H2P);
        unsigned vC = *(const unsigned*)(rowp + (size_t)pC.x * H2P);
        unsigned vD = *(const unsigned*)(rowp + (size_t)pD.x * H2P);
        unsigned vE = *(const unsigned*)(rowp + (size_t)pE.x * H2P);
        unsigned vF = *(const unsigned*)(rowp + (size_t)pF.x * H2P);
        unsigned vG = *(const unsigned*)(rowp + (size_t)pG.x * H2P);
        unsigned vH = *(const unsigned*)(rowp + (size_t)pH.x * H2P);
        float wA = __int_as_float(pA.y), wB = __int_as_float(pB.y);
        float wC = __int_as_float(pC.y), wD = __int_as_float(pD.y);
        float wE = __int_as_float(pE.y), wF = __int_as_float(pF.y);
        float wG = __int_as_float(pG.y), wH = __int_as_float(pH.y);
        acc.x = fmaf(wA, blo(vA), acc.x); acc.y = fmaf(wA, bhi(vA), acc.y);
        acc.x = fmaf(wB, blo(vB), acc.x); acc.y = fmaf(wB, bhi(vB), acc.y);
        acc.x = fmaf(wC, blo(vC), acc.x); acc.y = fmaf(wC, bhi(vC), acc.y);
        acc.x = fmaf(wD, blo(vD), acc.x); acc.y = fmaf(wD, bhi(vD), acc.y);
        acc.x = fmaf(wE, blo(vE), acc.x); acc.y = fmaf(wE, bhi(vE), acc.y);
        acc.x = fmaf(wF, blo(vF), acc.x); acc.y = fmaf(wF, bhi(vF), acc.y);
        acc.x = fmaf(wG, blo(vG), acc.x); acc.y = fmaf(wG, bhi(vG), acc.y);
        acc.x = fmaf(wH, blo(vH), acc.x); acc.y = fmaf(wH, bhi(vH), acc.y);
    }
    if (e < hi) {
        int2 pA = csr[e + 0 + h], pB = csr[e + 2 + h];
        int2 pC = csr[e + 4 + h], pD = csr[e + 6 + h];
        unsigned vA = *(const unsigned*)(rowp + (size_t)pA.x * H2P);
        unsigned vB = *(const unsigned*)(rowp + (size_t)pB.x * H2P);
        unsigned vC = *(const unsigned*)(rowp + (size_t)pC.x * H2P);
        unsigned vD = *(const unsigned*)(rowp + (size_t)pD.x * H2P);
        float wA = __int_as_float(pA.y), wB = __int_as_float(pB.y);
        float wC = __int_as_float(pC.y), wD = __int_as_float(pD.y);
        acc.x = fmaf(wA, blo(vA), acc.x); acc.y = fmaf(wA, bhi(vA), acc.y);
        acc.x = fmaf(wB, blo(vB), acc.x); acc.y = fmaf(wB, bhi(vB), acc.y);
        acc.x = fmaf(wC, blo(vC), acc.x); acc.y = fmaf(wC, bhi(vC), acc.y);
        acc.x = fmaf(wD, blo(vD), acc.x); acc.y = fmaf(wD, bhi(vD), acc.y);
    }
    acc.x += __shfl_xor(acc.x, 32);
    acc.y += __shfl_xor(acc.y, 32);

    float v0 = -1e30f, v1 = -1e30f;
    if (act) {
        v0 = acc.x + b2[2 * q];
        v1 = (2 * q + 1 < NCLASS) ? (acc.y + b2[2 * q + 1]) : -1e30f;
    }
    float pm = fmaxf(v0, v1);
    #pragma unroll
    for (int off = 16; off; off >>= 1) pm = fmaxf(pm, __shfl_xor(pm, off));
    float ex = 0.f;
    if (act) {
        ex = __expf(v0 - pm);
        if (2 * q + 1 < NCLASS) ex += __expf(v1 - pm);
    }
    #pragma unroll
    for (int off = 16; off; off >>= 1) ex += __shfl_xor(ex, off);
    if (h == 0 && act) {
        float ls = pm + __logf(ex);
        out[(size_t)i * NCLASS + 2 * q] = v0 - ls;
        if (2 * q + 1 < NCLASS) out[(size_t)i * NCLASS + 2 * q + 1] = v1 - ls;
    }
}

// ---------------- launch ----------------

extern "C" void kernel_launch(void* const* d_in, const int* in_sizes, int n_in,
                              void* d_out, int out_size, void* d_ws, size_t ws_size,
                              hipStream_t stream) {
    const float* x  = (const float*)d_in[0];
    const int*   ei = (const int*)d_in[1];
    const float* ew = (const float*)d_in[2];
    const float* W1 = (const float*)d_in[3];
    const float* b1 = (const float*)d_in[4];
    const float* W2 = (const float*)d_in[5];
    const float* b2 = (const float*)d_in[6];
    float* out = (float*)d_out;

    const int* e_src = ei;
    const int* e_dst = ei + N_EDGES;

    char* p = (char*)d_ws;
    auto carve = [&](size_t bytes) { void* r = (void*)p; p += (bytes + 255) & ~(size_t)255; return r; };
    unsigned long long* packed = (unsigned long long*)carve((size_t)N_NODES * NSUB * 8);
    float*  dinv      = (float*) carve(N_NODES * 4);
    int*    counts    = (int*)   carve(N_NODES * 4);
    int*    row_start = (int*)   carve(N_NODES * 4);
    int*    sub_base  = (int*)   carve((size_t)N_NODES * NSUB * 4);
    int*    total     = (int*)   carve(4);
    int*    pos       = (int*)   carve((size_t)N_EDGES * 4);
    int2*   csr       = (int2*)  carve((size_t)CSR_MAX * 8);
    ushort* h1b       = (ushort*)carve((size_t)N_NODES * NHID * 2);
    ushort* haggb     = (ushort*)carve((size_t)N_NODES * NHID * 2);
    ushort* h2b       = (ushort*)carve((size_t)N_NODES * H2P * 2);
    ushort* w1t       = (ushort*)carve((size_t)NHID * NFEAT * 2);
    ushort* w2t       = (ushort*)carve((size_t)H2P * NHID * 2);

    init_kernel<<<(N_NODES * NSUB + 255) / 256, 256, 0, stream>>>(packed, total, W1, W2, w1t, w2t);
    degcnt_kernel<<<(N_EDGES + 255) / 256, 256, 0, stream>>>(e_dst, ew, packed, pos, N_EDGES);
    segalloc_kernel<<<(N_NODES + 255) / 256, 256, 0, stream>>>(packed, counts, dinv,
                                                               row_start, sub_base, total,
                                                               csr, N_NODES);
    scatter_kernel<<<(N_EDGES + 255) / 256, 256, 0, stream>>>(e_src, e_dst, ew, pos, dinv,
                                                              row_start, sub_base, csr, N_EDGES);
    gemm1_kernel<<<(N_NODES + 63) / 64, 256, 0, stream>>>(x, w1t, h1b);
    agg1_kernel<<<(N_NODES + 3) / 4, 256, 0, stream>>>(h1b, row_start, counts, csr, dinv, b1, haggb);
    gemm2_kernel<<<(N_NODES + 63) / 64, 256, 0, stream>>>(haggb, w2t, h2b);
    agg2_kernel<<<(N_NODES + 3) / 4, 256, 0, stream>>>(h2b, row_start, counts, csr, dinv, b2, out, N_NODES);
}

// Round 12
// 150.049 us; speedup vs baseline: 1.5308x; 1.0835x over previous
//
#include <hip/hip_runtime.h>

#define N_NODES 50000
#define N_EDGES 800000
#define NFEAT   256
#define NHID    128
#define NCLASS  47
#define H2P     48    // padded h2 row (bf16)
#define CSR_MAX (N_EDGES + 7 * N_NODES)   // every segment padded to multiple of 8
#define NSUB    8     // sub-bucketed degree counters, strided layout packed[b*N+d]
#define G1_BLOCKS ((N_NODES + 63) / 64)   // 782 gemm1 blocks inside the fused kernel

typedef __attribute__((ext_vector_type(8))) short short8v;
typedef __attribute__((ext_vector_type(4))) float f32x4;

__device__ __forceinline__ ushort f2bf(float f) {
    unsigned u = __float_as_uint(f);
    unsigned r = (u + 0x7FFF + ((u >> 16) & 1)) >> 16;   // round-to-nearest-even
    return (ushort)r;
}
__device__ __forceinline__ float blo(unsigned u) { return __uint_as_float(u << 16); }
__device__ __forceinline__ float bhi(unsigned u) { return __uint_as_float(u & 0xFFFF0000u); }

// ------- init: zero packed counters + total, and prep bf16 transposed weights -------

__global__ void init_kernel(unsigned long long* __restrict__ packed,
                            int* __restrict__ total,
                            const float* __restrict__ W1, const float* __restrict__ W2,
                            ushort* __restrict__ w1t, ushort* __restrict__ w2t) {
    int t = blockIdx.x * blockDim.x + threadIdx.x;
    if (t < N_NODES * NSUB) packed[t] = 0ull;
    if (t == 0) *total = 0;
    if (t < NFEAT * NHID) {              // read coalesced over c-fast
        int k = t >> 7, c = t & 127;
        w1t[c * NFEAT + k] = f2bf(W1[(size_t)k * NHID + c]);
    }
    if (t < NHID * H2P) {
        int k = t / H2P, c = t % H2P;
        w2t[c * NHID + k] = (c < NCLASS) ? f2bf(W2[(size_t)k * NCLASS + c]) : 0;
    }
}

// ---------------- FUSED: gemm1 (blocks 0..781) + degcnt (blocks 782..) ----------------
// gemm1: h1b = bf16(x @ W1) via MFMA, B from pre-transposed w1t.
// degcnt: one 64-bit atomic per edge; packed[b*N+d] strided across lines;
//         returned old count doubles as the CSR slot index. Independent work —
//         gemm1's compute hides inside degcnt's atomic-latency shadow.

__global__ __launch_bounds__(256) void fused_gemm1_degcnt_kernel(
        const float* __restrict__ x, const ushort* __restrict__ w1t,
        ushort* __restrict__ h1b,
        const int* __restrict__ dst, const float* __restrict__ w,
        unsigned long long* __restrict__ packed, int* __restrict__ pos) {
    __shared__ __align__(16) ushort xs[64][72];
    __shared__ __align__(16) ushort ws[128][72];
    int tid = threadIdx.x;
    if (blockIdx.x >= G1_BLOCKS) {
        // ---- degcnt body ----
        int e = (blockIdx.x - G1_BLOCKS) * 256 + tid;
        if (e < N_EDGES) {
            int d = dst[e];
            int b = e & (NSUB - 1);
            unsigned fx = __float2uint_rn(w[e] * 1048576.0f);
            unsigned long long old = atomicAdd(&packed[(size_t)b * N_NODES + d],
                                               (1ull << 40) | (unsigned long long)fx);
            pos[e] = (int)(old >> 40);
        }
        return;
    }
    // ---- gemm1 body ----
    int node0 = blockIdx.x * 64;
    int wave = tid >> 6, l = tid & 63;
    int fr = l & 15, fq = l >> 4;
    int r0 = (wave >> 1) * 32;
    int c0 = (wave & 1) * 64;

    f32x4 acc[2][4] = {};

    for (int kk0 = 0; kk0 < NFEAT; kk0 += 64) {
        {
            int row = tid >> 2, q = tid & 3;
            int srow = node0 + row; if (srow >= N_NODES) srow = N_NODES - 1;
            const float4* src = (const float4*)(x + (size_t)srow * NFEAT + kk0 + q * 16);
            ushort tmp[16];
            #pragma unroll
            for (int i = 0; i < 4; ++i) {
                float4 v = src[i];
                tmp[i * 4 + 0] = f2bf(v.x); tmp[i * 4 + 1] = f2bf(v.y);
                tmp[i * 4 + 2] = f2bf(v.z); tmp[i * 4 + 3] = f2bf(v.w);
            }
            #pragma unroll
            for (int i = 0; i < 2; ++i)
                *(short8v*)&xs[row][q * 16 + i * 8] = *(short8v*)&tmp[i * 8];
        }
        {
            int rr = tid >> 3;
            int cq = tid & 7;
            #pragma unroll
            for (int i = 0; i < 4; ++i) {
                int row = rr + i * 32;
                *(short8v*)&ws[row][cq * 8] =
                    *(const short8v*)&w1t[(size_t)row * NFEAT + kk0 + cq * 8];
            }
        }
        __syncthreads();
        short8v a[2][2], b[4][2];
        #pragma unroll
        for (int m = 0; m < 2; ++m)
            #pragma unroll
            for (int kf = 0; kf < 2; ++kf)
                a[m][kf] = *(const short8v*)&xs[r0 + m * 16 + fr][kf * 32 + fq * 8];
        #pragma unroll
        for (int n = 0; n < 4; ++n)
            #pragma unroll
            for (int kf = 0; kf < 2; ++kf)
                b[n][kf] = *(const short8v*)&ws[c0 + n * 16 + fr][kf * 32 + fq * 8];
        #pragma unroll
        for (int m = 0; m < 2; ++m)
            #pragma unroll
            for (int n = 0; n < 4; ++n)
                #pragma unroll
                for (int kf = 0; kf < 2; ++kf)
                    acc[m][n] = __builtin_amdgcn_mfma_f32_16x16x32_bf16(
                        a[m][kf], b[n][kf], acc[m][n], 0, 0, 0);
        __syncthreads();
    }
    #pragma unroll
    for (int m = 0; m < 2; ++m) {
        #pragma unroll
        for (int n = 0; n < 4; ++n) {
            #pragma unroll
            for (int j = 0; j < 4; ++j) {
                int gr = node0 + r0 + m * 16 + fq * 4 + j;
                if (gr < N_NODES)
                    h1b[(size_t)gr * NHID + c0 + n * 16 + fr] = f2bf(acc[m][n][j]);
            }
        }
    }
}

// segment allocator + dinv + pad-writer: block-local scan + one atomicAdd per block.
// Strided packed reads are fully coalesced (consecutive i -> consecutive addresses).
__global__ __launch_bounds__(256) void segalloc_kernel(const unsigned long long* __restrict__ packed,
                                                       int* __restrict__ counts,
                                                       float* __restrict__ dinv,
                                                       int* __restrict__ row_start,
                                                       int* __restrict__ sub_base,
                                                       int* __restrict__ total,
                                                       int2* __restrict__ csr, int n) {
    __shared__ int s[256];
    __shared__ int base_s;
    int t = threadIdx.x;
    int i = blockIdx.x * 256 + t;
    int v = 0, cnt = 0;
    if (i < n) {
        unsigned long long ws = 0;
        int sb[NSUB];
        #pragma unroll
        for (int b = 0; b < NSUB; ++b) {
            unsigned long long pk = packed[(size_t)b * N_NODES + i];
            sb[b] = cnt;
            cnt += (int)(pk >> 40);
            ws += (pk & 0xFFFFFFFFFFull);
        }
        counts[i] = cnt;
        float deg = 1.0f + (float)ws * (1.0f / 1048576.0f);
        dinv[i] = rsqrtf(deg);
        #pragma unroll
        for (int b = 0; b < NSUB; b += 4)
            *(int4*)&sub_base[(size_t)i * NSUB + b] = make_int4(sb[b], sb[b+1], sb[b+2], sb[b+3]);
        v = (cnt + 7) & ~7;
    }
    s[t] = v;
    __syncthreads();
    #pragma unroll
    for (int off = 1; off < 256; off <<= 1) {
        int x = s[t];
        if (t >= off) x += s[t - off];
        __syncthreads();
        s[t] = x;
        __syncthreads();
    }
    if (t == 255) base_s = atomicAdd(total, s[255]);
    __syncthreads();
    if (i < n) {
        int base = base_s + s[t] - v;
        row_start[i] = base;
        for (int k = cnt; k < v; ++k) csr[base + k] = make_int2(0, 0);  // pads
    }
}

// atomic-free scatter: slot = row_start[d] + sub_base[d][b] + pos[e]
__global__ void scatter_kernel(const int* __restrict__ src, const int* __restrict__ dst,
                               const float* __restrict__ w, const int* __restrict__ pos,
                               const float* __restrict__ dinv,
                               const int* __restrict__ row_start,
                               const int* __restrict__ sub_base,
                               int2* __restrict__ csr, int E) {
    int e = blockIdx.x * blockDim.x + threadIdx.x;
    if (e >= E) return;
    int d = dst[e], s = src[e];
    int b = e & (NSUB - 1);
    int p = row_start[d] + sub_base[(size_t)d * NSUB + b] + pos[e];
    int2 pr;
    pr.x = s;
    pr.y = __float_as_int(dinv[s] * w[e] * dinv[d]);
    csr[p] = pr;
}

// ---------------- Aggregation 1: haggb = bf16(relu(A_norm @ h1 + b1)) ----------------
// one WAVE per node; lane=(half h, quarter q); 8B gathers; 16-edge unroll.

__global__ __launch_bounds__(256) void agg1_kernel(const ushort* __restrict__ h1b,
                                                   const int* __restrict__ row_start,
                                                   const int* __restrict__ counts,
                                                   const int2* __restrict__ csr,
                                                   const float* __restrict__ dinv,
                                                   const float* __restrict__ b1,
                                                   ushort* __restrict__ haggb) {
    int wv = threadIdx.x >> 6;
    int i = blockIdx.x * 4 + wv;
    int l = threadIdx.x & 63;
    int h = l >> 5, q = l & 31;
    const ushort* rowp = h1b + 4 * q;    // this lane's 4-feature slice

    float di = dinv[i];
    float sc = (h == 0) ? di * di : 0.f;
    uint2 sv = *(const uint2*)(rowp + (size_t)i * NHID);
    float4 acc;
    acc.x = sc * blo(sv.x); acc.y = sc * bhi(sv.x);
    acc.z = sc * blo(sv.y); acc.w = sc * bhi(sv.y);

    int lo = row_start[i], hi = lo + ((counts[i] + 7) & ~7);
    int e = lo;
    for (; e + 16 <= hi; e += 16) {
        int2 pA = csr[e + 0 + h],  pB = csr[e + 2 + h];
        int2 pC = csr[e + 4 + h],  pD = csr[e + 6 + h];
        int2 pE = csr[e + 8 + h],  pF = csr[e + 10 + h];
        int2 pG = csr[e + 12 + h], pH = csr[e + 14 + h];
        uint2 vA = *(const uint2*)(rowp + (size_t)pA.x * NHID);
        uint2 vB = *(const uint2*)(rowp + (size_t)pB.x * NHID);
        uint2 vC = *(const uint2*)(rowp + (size_t)pC.x * NHID);
        uint2 vD = *(const uint2*)(rowp + (size_t)pD.x * NHID);
        uint2 vE = *(const uint2*)(rowp + (size_t)pE.x * NHID);
        uint2 vF = *(const uint2*)(rowp + (size_t)pF.x * NHID);
        uint2 vG = *(const uint2*)(rowp + (size_t)pG.x * NHID);
        uint2 vH = *(const uint2*)(rowp + (size_t)pH.x * NHID);
        float wA = __int_as_float(pA.y), wB = __int_as_float(pB.y);
        float wC = __int_as_float(pC.y), wD = __int_as_float(pD.y);
        float wE = __int_as_float(pE.y), wF = __int_as_float(pF.y);
        float wG = __int_as_float(pG.y), wH = __int_as_float(pH.y);
        acc.x = fmaf(wA, blo(vA.x), acc.x); acc.y = fmaf(wA, bhi(vA.x), acc.y);
        acc.z = fmaf(wA, blo(vA.y), acc.z); acc.w = fmaf(wA, bhi(vA.y), acc.w);
        acc.x = fmaf(wB, blo(vB.x), acc.x); acc.y = fmaf(wB, bhi(vB.x), acc.y);
        acc.z = fmaf(wB, blo(vB.y), acc.z); acc.w = fmaf(wB, bhi(vB.y), acc.w);
        acc.x = fmaf(wC, blo(vC.x), acc.x); acc.y = fmaf(wC, bhi(vC.x), acc.y);
        acc.z = fmaf(wC, blo(vC.y), acc.z); acc.w = fmaf(wC, bhi(vC.y), acc.w);
        acc.x = fmaf(wD, blo(vD.x), acc.x); acc.y = fmaf(wD, bhi(vD.x), acc.y);
        acc.z = fmaf(wD, blo(vD.y), acc.z); acc.w = fmaf(wD, bhi(vD.y), acc.w);
        acc.x = fmaf(wE, blo(vE.x), acc.x); acc.y = fmaf(wE, bhi(vE.x), acc.y);
        acc.z = fmaf(wE, blo(vE.y), acc.z); acc.w = fmaf(wE, bhi(vE.y), acc.w);
        acc.x = fmaf(wF, blo(vF.x), acc.x); acc.y = fmaf(wF, bhi(vF.x), acc.y);
        acc.z = fmaf(wF, blo(vF.y), acc.z); acc.w = fmaf(wF, bhi(vF.y), acc.w);
        acc.x = fmaf(wG, blo(vG.x), acc.x); acc.y = fmaf(wG, bhi(vG.x), acc.y);
        acc.z = fmaf(wG, blo(vG.y), acc.z); acc.w = fmaf(wG, bhi(vG.y), acc.w);
        acc.x = fmaf(wH, blo(vH.x), acc.x); acc.y = fmaf(wH, bhi(vH.x), acc.y);
        acc.z = fmaf(wH, blo(vH.y), acc.z); acc.w = fmaf(wH, bhi(vH.y), acc.w);
    }
    if (e < hi) {   // one remaining 8-edge group
        int2 pA = csr[e + 0 + h], pB = csr[e + 2 + h];
        int2 pC = csr[e + 4 + h], pD = csr[e + 6 + h];
        uint2 vA = *(const uint2*)(rowp + (size_t)pA.x * NHID);
        uint2 vB = *(const uint2*)(rowp + (size_t)pB.x * NHID);
        uint2 vC = *(const uint2*)(rowp + (size_t)pC.x * NHID);
        uint2 vD = *(const uint2*)(rowp + (size_t)pD.x * NHID);
        float wA = __int_as_float(pA.y), wB = __int_as_float(pB.y);
        float wC = __int_as_float(pC.y), wD = __int_as_float(pD.y);
        acc.x = fmaf(wA, blo(vA.x), acc.x); acc.y = fmaf(wA, bhi(vA.x), acc.y);
        acc.z = fmaf(wA, blo(vA.y), acc.z); acc.w = fmaf(wA, bhi(vA.y), acc.w);
        acc.x = fmaf(wB, blo(vB.x), acc.x); acc.y = fmaf(wB, bhi(vB.x), acc.y);
        acc.z = fmaf(wB, blo(vB.y), acc.z); acc.w = fmaf(wB, bhi(vB.y), acc.w);
        acc.x = fmaf(wC, blo(vC.x), acc.x); acc.y = fmaf(wC, bhi(vC.x), acc.y);
        acc.z = fmaf(wC, blo(vC.y), acc.z); acc.w = fmaf(wC, bhi(vC.y), acc.w);
        acc.x = fmaf(wD, blo(vD.x), acc.x); acc.y = fmaf(wD, bhi(vD.x), acc.y);
        acc.z = fmaf(wD, blo(vD.y), acc.z); acc.w = fmaf(wD, bhi(vD.y), acc.w);
    }
    acc.x += __shfl_xor(acc.x, 32);
    acc.y += __shfl_xor(acc.y, 32);
    acc.z += __shfl_xor(acc.z, 32);
    acc.w += __shfl_xor(acc.w, 32);
    if (h == 0) {
        float4 bb = *(const float4*)(b1 + 4 * q);
        acc.x = fmaxf(acc.x + bb.x, 0.f);
        acc.y = fmaxf(acc.y + bb.y, 0.f);
        acc.z = fmaxf(acc.z + bb.z, 0.f);
        acc.w = fmaxf(acc.w + bb.w, 0.f);
        uint2 o;
        o.x = (unsigned)f2bf(acc.x) | ((unsigned)f2bf(acc.y) << 16);
        o.y = (unsigned)f2bf(acc.z) | ((unsigned)f2bf(acc.w) << 16);
        *(uint2*)(haggb + (size_t)i * NHID + 4 * q) = o;
    }
}

// ---------------- Layer 2 GEMM (MFMA bf16): h2b = bf16(hagg @ W2), rows padded to 48 ----------------

__global__ __launch_bounds__(256) void gemm2_kernel(const ushort* __restrict__ haggb,
                                                    const ushort* __restrict__ w2t,
                                                    ushort* __restrict__ h2b) {
    __shared__ __align__(16) ushort ha[64][136];
    __shared__ __align__(16) ushort wt[48][136];
    int tid = threadIdx.x;
    int node0 = blockIdx.x * 64;
    {
        int row = tid >> 2, q = tid & 3;
        int srow = node0 + row; if (srow >= N_NODES) srow = N_NODES - 1;
        const short8v* src = (const short8v*)(haggb + (size_t)srow * NHID + q * 32);
        #pragma unroll
        for (int i = 0; i < 4; ++i)
            *(short8v*)&ha[row][q * 32 + i * 8] = src[i];
    }
    {
        #pragma unroll
        for (int i = 0; i < 3; ++i) {
            int id = tid + i * 256;
            int row = id >> 4, cq = id & 15;
            *(short8v*)&wt[row][cq * 8] =
                *(const short8v*)&w2t[(size_t)row * NHID + cq * 8];
        }
    }
    __syncthreads();
    int wave = tid >> 6, l = tid & 63;
    int fr = l & 15, fq = l >> 4;
    int r0 = wave * 16;
    short8v a[4], b[3][4];
    #pragma unroll
    for (int kf = 0; kf < 4; ++kf)
        a[kf] = *(const short8v*)&ha[r0 + fr][kf * 32 + fq * 8];
    #pragma unroll
    for (int n = 0; n < 3; ++n)
        #pragma unroll
        for (int kf = 0; kf < 4; ++kf)
            b[n][kf] = *(const short8v*)&wt[n * 16 + fr][kf * 32 + fq * 8];
    f32x4 acc[3] = {};
    #pragma unroll
    for (int n = 0; n < 3; ++n)
        #pragma unroll
        for (int kf = 0; kf < 4; ++kf)
            acc[n] = __builtin_amdgcn_mfma_f32_16x16x32_bf16(a[kf], b[n][kf], acc[n], 0, 0, 0);
    #pragma unroll
    for (int n = 0; n < 3; ++n) {
        #pragma unroll
        for (int j = 0; j < 4; ++j) {
            int gr = node0 + r0 + fq * 4 + j;
            int col = n * 16 + fr;
            if (gr < N_NODES && col < H2P)
                h2b[(size_t)gr * H2P + col] = (col < NCLASS) ? f2bf(acc[n][j]) : 0;
        }
    }
}

// ---------------- Aggregation 2 + bias + log_softmax -> out ----------------

__global__ __launch_bounds__(256) void agg2_kernel(const ushort* __restrict__ h2b,
                                                   const int* __restrict__ row_start,
                                                   const int* __restrict__ counts,
                                                   const int2* __restrict__ csr,
                                                   const float* __restrict__ dinv,
                                                   const float* __restrict__ b2,
                                                   float* __restrict__ out, int n) {
    int wv = threadIdx.x >> 6;
    int i = blockIdx.x * 4 + wv;
    if (i >= n) return;
    int l = threadIdx.x & 63;
    int h = l >> 5, q = l & 31;
    bool act = q < 24;
    int qq = act ? q : 0;
    const ushort* rowp = h2b + 2 * qq;   // this lane's 2-feature slice

    float di = dinv[i];
    float sc = (h == 0 && act) ? di * di : 0.f;
    unsigned sv = *(const unsigned*)(rowp + (size_t)i * H2P);
    float2 acc;
    acc.x = sc * blo(sv); acc.y = sc * bhi(sv);

    int lo = row_start[i], hi = lo + ((counts[i] + 7) & ~7);
    int e = lo;
    for (; e + 16 <= hi; e += 16) {
        int2 pA = csr[e + 0 + h],  pB = csr[e + 2 + h];
        int2 pC = csr[e + 4 + h],  pD = csr[e + 6 + h];
        int2 pE = csr[e + 8 + h],  pF = csr[e + 10 + h];
        int2 pG = csr[e + 12 + h], pH = csr[e + 14 + h];
        unsigned vA = *(const unsigned*)(rowp + (size_t)pA.x * H2P);
        unsigned vB = *(const unsigned*)(rowp + (size_t)pB.x * H2P);
        unsigned vC = *(const unsigned*)(rowp + (size_t)pC.x * H2P);
        unsigned vD = *(const unsigned*)(rowp + (size_t)pD.x * H2P);
        unsigned vE = *(const unsigned*)(rowp + (size_t)pE.x * H2P);
        unsigned vF = *(const unsigned*)(rowp + (size_t)pF.x * H2P);
        unsigned vG = *(const unsigned*)(rowp + (size_t)pG.x * H2P);
        unsigned vH = *(const unsigned*)(rowp + (size_t)pH.x * H2P);
        float wA = __int_as_float(pA.y), wB = __int_as_float(pB.y);
        float wC = __int_as_float(pC.y), wD = __int_as_float(pD.y);
        float wE = __int_as_float(pE.y), wF = __int_as_float(pF.y);
        float wG = __int_as_float(pG.y), wH = __int_as_float(pH.y);
        acc.x = fmaf(wA, blo(vA), acc.x); acc.y = fmaf(wA, bhi(vA), acc.y);
        acc.x = fmaf(wB, blo(vB), acc.x); acc.y = fmaf(wB, bhi(vB), acc.y);
        acc.x = fmaf(wC, blo(vC), acc.x); acc.y = fmaf(wC, bhi(vC), acc.y);
        acc.x = fmaf(wD, blo(vD), acc.x); acc.y = fmaf(wD, bhi(vD), acc.y);
        acc.x = fmaf(wE, blo(vE), acc.x); acc.y = fmaf(wE, bhi(vE), acc.y);
        acc.x = fmaf(wF, blo(vF), acc.x); acc.y = fmaf(wF, bhi(vF), acc.y);
        acc.x = fmaf(wG, blo(vG), acc.x); acc.y = fmaf(wG, bhi(vG), acc.y);
        acc.x = fmaf(wH, blo(vH), acc.x); acc.y = fmaf(wH, bhi(vH), acc.y);
    }
    if (e < hi) {
        int2 pA = csr[e + 0 + h], pB = csr[e + 2 + h];
        int2 pC = csr[e + 4 + h], pD = csr[e + 6 + h];
        unsigned vA = *(const unsigned*)(rowp + (size_t)pA.x * H2P);
        unsigned vB = *(const unsigned*)(rowp + (size_t)pB.x * H2P);
        unsigned vC = *(const unsigned*)(rowp + (size_t)pC.x * H2P);
        unsigned vD = *(const unsigned*)(rowp + (size_t)pD.x * H2P);
        float wA = __int_as_float(pA.y), wB = __int_as_float(pB.y);
        float wC = __int_as_float(pC.y), wD = __int_as_float(pD.y);
        acc.x = fmaf(wA, blo(vA), acc.x); acc.y = fmaf(wA, bhi(vA), acc.y);
        acc.x = fmaf(wB, blo(vB), acc.x); acc.y = fmaf(wB, bhi(vB), acc.y);
        acc.x = fmaf(wC, blo(vC), acc.x); acc.y = fmaf(wC, bhi(vC), acc.y);
        acc.x = fmaf(wD, blo(vD), acc.x); acc.y = fmaf(wD, bhi(vD), acc.y);
    }
    acc.x += __shfl_xor(acc.x, 32);
    acc.y += __shfl_xor(acc.y, 32);

    float v0 = -1e30f, v1 = -1e30f;
    if (act) {
        v0 = acc.x + b2[2 * q];
        v1 = (2 * q + 1 < NCLASS) ? (acc.y + b2[2 * q + 1]) : -1e30f;
    }
    float pm = fmaxf(v0, v1);
    #pragma unroll
    for (int off = 16; off; off >>= 1) pm = fmaxf(pm, __shfl_xor(pm, off));
    float ex = 0.f;
    if (act) {
        ex = __expf(v0 - pm);
        if (2 * q + 1 < NCLASS) ex += __expf(v1 - pm);
    }
    #pragma unroll
    for (int off = 16; off; off >>= 1) ex += __shfl_xor(ex, off);
    if (h == 0 && act) {
        float ls = pm + __logf(ex);
        out[(size_t)i * NCLASS + 2 * q] = v0 - ls;
        if (2 * q + 1 < NCLASS) out[(size_t)i * NCLASS + 2 * q + 1] = v1 - ls;
    }
}

// ---------------- launch ----------------

extern "C" void kernel_launch(void* const* d_in, const int* in_sizes, int n_in,
                              void* d_out, int out_size, void* d_ws, size_t ws_size,
                              hipStream_t stream) {
    const float* x  = (const float*)d_in[0];
    const int*   ei = (const int*)d_in[1];
    const float* ew = (const float*)d_in[2];
    const float* W1 = (const float*)d_in[3];
    const float* b1 = (const float*)d_in[4];
    const float* W2 = (const float*)d_in[5];
    const float* b2 = (const float*)d_in[6];
    float* out = (float*)d_out;

    const int* e_src = ei;
    const int* e_dst = ei + N_EDGES;

    char* p = (char*)d_ws;
    auto carve = [&](size_t bytes) { void* r = (void*)p; p += (bytes + 255) & ~(size_t)255; return r; };
    unsigned long long* packed = (unsigned long long*)carve((size_t)N_NODES * NSUB * 8);
    float*  dinv      = (float*) carve(N_NODES * 4);
    int*    counts    = (int*)   carve(N_NODES * 4);
    int*    row_start = (int*)   carve(N_NODES * 4);
    int*    sub_base  = (int*)   carve((size_t)N_NODES * NSUB * 4);
    int*    total     = (int*)   carve(4);
    int*    pos       = (int*)   carve((size_t)N_EDGES * 4);
    int2*   csr       = (int2*)  carve((size_t)CSR_MAX * 8);
    ushort* h1b       = (ushort*)carve((size_t)N_NODES * NHID * 2);
    ushort* haggb     = (ushort*)carve((size_t)N_NODES * NHID * 2);
    ushort* h2b       = (ushort*)carve((size_t)N_NODES * H2P * 2);
    ushort* w1t       = (ushort*)carve((size_t)NHID * NFEAT * 2);
    ushort* w2t       = (ushort*)carve((size_t)H2P * NHID * 2);

    init_kernel<<<(N_NODES * NSUB + 255) / 256, 256, 0, stream>>>(packed, total, W1, W2, w1t, w2t);
    fused_gemm1_degcnt_kernel<<<G1_BLOCKS + (N_EDGES + 255) / 256, 256, 0, stream>>>(
        x, w1t, h1b, e_dst, ew, packed, pos);
    segalloc_kernel<<<(N_NODES + 255) / 256, 256, 0, stream>>>(packed, counts, dinv,
                                                               row_start, sub_base, total,
                                                               csr, N_NODES);
    scatter_kernel<<<(N_EDGES + 255) / 256, 256, 0, stream>>>(e_src, e_dst, ew, pos, dinv,
                                                              row_start, sub_base, csr, N_EDGES);
    agg1_kernel<<<(N_NODES + 3) / 4, 256, 0, stream>>>(h1b, row_start, counts, csr, dinv, b1, haggb);
    gemm2_kernel<<<(N_NODES + 63) / 64, 256, 0, stream>>>(haggb, w2t, h2b);
    agg2_kernel<<<(N_NODES + 3) / 4, 256, 0, stream>>>(h2b, row_start, counts, csr, dinv, b2, out, N_NODES);
}